// Round 9
// baseline (273.753 us; speedup 1.0000x reference)
//
#include <hip/hip_runtime.h>
#include <stdint.h>

// Problem constants
static constexpr int B_ROWS = 8192;
static constexpr int C_COLS = 1024;
static constexpr uint32_t HALF_N = 4194304u;  // B*C/2
static constexpr int NPAIR = B_ROWS / 2;      // 4096 row-pairs

// d_ws is re-poisoned to 0xAA bytes before every launch, so every uint32
// in it starts at exactly 0xAAAAAAAA. Completion counters exploit this.
static constexpr uint32_t POISON = 0xAAAAAAAAu;
static constexpr int NGROUP = 8;                     // level-1 counters
static constexpr uint32_t GROUP_QUOTA = NPAIR / NGROUP;  // 512 blocks/counter

__device__ __forceinline__ uint32_t rotl32(uint32_t x, int d) {
  return (x << d) | (x >> (32 - d));
}

// JAX Threefry-2x32 with key (0, 42), 20 rounds. (verified bit-exact R0-R8)
__device__ __forceinline__ void threefry2x32_k42(uint32_t& x0, uint32_t& x1) {
  const uint32_t ks0 = 0u;
  const uint32_t ks1 = 42u;
  const uint32_t ks2 = 0u ^ 42u ^ 0x1BD11BDAu;
  x0 += ks0; x1 += ks1;
#define TF_R(r) { x0 += x1; x1 = rotl32(x1, (r)); x1 ^= x0; }
  TF_R(13) TF_R(15) TF_R(26) TF_R(6)
  x0 += ks1; x1 += ks2 + 1u;
  TF_R(17) TF_R(29) TF_R(16) TF_R(24)
  x0 += ks2; x1 += ks0 + 2u;
  TF_R(13) TF_R(15) TF_R(26) TF_R(6)
  x0 += ks0; x1 += ks1 + 3u;
  TF_R(17) TF_R(29) TF_R(16) TF_R(24)
  x0 += ks1; x1 += ks2 + 4u;
  TF_R(13) TF_R(15) TF_R(26) TF_R(6)
  x0 += ks2; x1 += ks0 + 5u;
#undef TF_R
}

// ---- DPP wave64 primitives (VALU only, no DS pipe) ----
__device__ __forceinline__ int wave_iscan_add(int x) {
  x += __builtin_amdgcn_update_dpp(0, x, 0x111, 0xf, 0xf, false);
  x += __builtin_amdgcn_update_dpp(0, x, 0x112, 0xf, 0xf, false);
  x += __builtin_amdgcn_update_dpp(0, x, 0x114, 0xf, 0xf, false);
  x += __builtin_amdgcn_update_dpp(0, x, 0x118, 0xf, 0xf, false);
  x += __builtin_amdgcn_update_dpp(0, x, 0x142, 0xa, 0xf, false);
  x += __builtin_amdgcn_update_dpp(0, x, 0x143, 0xc, 0xf, false);
  return x;  // lane63 holds the wave total
}

__device__ __forceinline__ uint32_t wave_min_u32(uint32_t x) {
  uint32_t t;
#define MSTEP(ctrl, rmask)                                                   \
  t = (uint32_t)__builtin_amdgcn_update_dpp(-1, (int)x, ctrl, rmask, 0xf, false); \
  x = (t < x) ? t : x;
  MSTEP(0x111, 0xf) MSTEP(0x112, 0xf) MSTEP(0x114, 0xf) MSTEP(0x118, 0xf)
  MSTEP(0x142, 0xa) MSTEP(0x143, 0xc)
#undef MSTEP
  return x;
}

__device__ __forceinline__ int wave_max_i32(int x) {  // inputs >= -1
  int t;
#define XSTEP(ctrl, rmask)                                                   \
  t = __builtin_amdgcn_update_dpp(-1, x, ctrl, rmask, 0xf, false);           \
  x = (t > x) ? t : x;
  XSTEP(0x111, 0xf) XSTEP(0x112, 0xf) XSTEP(0x114, 0xf) XSTEP(0x118, 0xf)
  XSTEP(0x142, 0xa) XSTEP(0x143, 0xc)
#undef XSTEP
  return x;
}

__device__ __forceinline__ float wave_fadd(float x) {
#define FSTEP(ctrl, rmask)                                                   \
  x += __int_as_float(                                                       \
      __builtin_amdgcn_update_dpp(0, __float_as_int(x), ctrl, rmask, 0xf, false));
  FSTEP(0x111, 0xf) FSTEP(0x112, 0xf) FSTEP(0x114, 0xf) FSTEP(0x118, 0xf)
  FSTEP(0x142, 0xa) FSTEP(0x143, 0xc)
#undef FSTEP
  return x;
}

// Block = 128 threads = 2 waves, one row-pair (rows p, p+4096) — R7
// structure verbatim, plus a fused last-block final reduction (two-level
// done-counters exploiting the 0xAA workspace poison; no separate
// finalize launch, no memset).
__global__ __launch_bounds__(128) void attr_loss_main(
    const float* __restrict__ scores, const int* __restrict__ attrs,
    float* __restrict__ partials, uint32_t* __restrict__ counters,
    float* __restrict__ out) {
  __shared__ int hist[2][256];
  __shared__ uint32_t xbuf[2][512];
  __shared__ int slast;
  __shared__ float fred[2];

  const int t = threadIdx.x;
  const int lane = t & 63;
  const int w = t >> 6;
  const int pair = blockIdx.x;
  const int myrow = pair + w * NPAIR;
  const int selfc0 = w * 512 + lane * 8;
  const int othc0 = (1 - w) * 512 + lane * 8;

  // ---- ALL global loads first: latency overlaps the threefry chain ----
  const float* srow = scores + (size_t)myrow * C_COLS;
  const int* arow = attrs + (size_t)myrow * C_COLS;
  const int4 a0 = *reinterpret_cast<const int4*>(arow + selfc0);
  const int4 a1 = *reinterpret_cast<const int4*>(arow + selfc0 + 4);
  const int4 a2 = *reinterpret_cast<const int4*>(arow + othc0);
  const int4 a3 = *reinterpret_cast<const int4*>(arow + othc0 + 4);
  const float4 s0 = *reinterpret_cast<const float4*>(srow + selfc0);
  const float4 s1 = *reinterpret_cast<const float4*>(srow + selfc0 + 4);
  const float4 s2 = *reinterpret_cast<const float4*>(srow + othc0);
  const float4 s3 = *reinterpret_cast<const float4*>(srow + othc0 + 4);

  // clear my wave-private histogram (same-wave LDS is program-ordered)
  *reinterpret_cast<int4*>(&hist[w][lane * 4]) = make_int4(0, 0, 0, 0);

  // threefry: 8 counter pairs -> keys for both rows of the pair
  uint32_t key[16];
#pragma unroll
  for (int j = 0; j < 8; ++j) {
    const int col = selfc0 + j;
    uint32_t x0 = (uint32_t)(pair * C_COLS + col);
    uint32_t x1 = x0 + HALF_N;
    threefry2x32_k42(x0, x1);
    const uint32_t cb = (uint32_t)col >> 1;
    const uint32_t k0 = (x0 & 0xFFFFFE00u) | cb;
    const uint32_t k1 = (x1 & 0xFFFFFE00u) | cb;
    key[j] = w ? k1 : k0;
    xbuf[w][j * 64 + lane] = w ? k0 : k1;
  }

  // zero-attr mask (attr loads have long arrived)
  uint32_t zm = 0u;
  zm |= (a0.x == 0 ? 1u : 0u) << 0;  zm |= (a0.y == 0 ? 1u : 0u) << 1;
  zm |= (a0.z == 0 ? 1u : 0u) << 2;  zm |= (a0.w == 0 ? 1u : 0u) << 3;
  zm |= (a1.x == 0 ? 1u : 0u) << 4;  zm |= (a1.y == 0 ? 1u : 0u) << 5;
  zm |= (a1.z == 0 ? 1u : 0u) << 6;  zm |= (a1.w == 0 ? 1u : 0u) << 7;
  zm |= (a2.x == 0 ? 1u : 0u) << 8;  zm |= (a2.y == 0 ? 1u : 0u) << 9;
  zm |= (a2.z == 0 ? 1u : 0u) << 10; zm |= (a2.w == 0 ? 1u : 0u) << 11;
  zm |= (a3.x == 0 ? 1u : 0u) << 12; zm |= (a3.y == 0 ? 1u : 0u) << 13;
  zm |= (a3.z == 0 ? 1u : 0u) << 14; zm |= (a3.w == 0 ? 1u : 0u) << 15;

  // self-half histogram adds: UNCONDITIONAL ds_add of the zm bit
#pragma unroll
  for (int e = 0; e < 8; ++e) {
    atomicAdd(&hist[w][key[e] >> 24], (int)((zm >> e) & 1u));
  }

  __syncthreads();
#pragma unroll
  for (int j = 0; j < 8; ++j) key[8 + j] = xbuf[1 - w][j * 64 + lane];

  // partner-half histogram adds
#pragma unroll
  for (int e = 8; e < 16; ++e) {
    atomicAdd(&hist[w][key[e] >> 24], (int)((zm >> e) & 1u));
  }

  // scan histogram, locate rank k-1 bucket
  const int4 hv = *reinterpret_cast<const int4*>(&hist[w][lane * 4]);
  const int c0 = hv.x, c1 = c0 + hv.y, c2 = c1 + hv.z, c3 = c2 + hv.w;
  const int incl = wave_iscan_add(c3);
  const int excl = incl - c3;
  const int n_zero = __builtin_amdgcn_readlane(incl, 63);
  const int k = (int)rintf(0.95f * (float)n_zero);

  uint32_t T = 0u;
  if (k > 0) {
    const int target = k - 1;
    int enc = -1;  // (bucket << 16) | within-bucket-rank; one lane sets it
    const int ce0 = excl, ce1 = excl + c0, ce2 = excl + c1, ce3 = excl + c2;
    if (hv.x > 0 && ce0 <= target && target < ce0 + hv.x) enc = ((lane * 4 + 0) << 16) | (target - ce0);
    if (hv.y > 0 && ce1 <= target && target < ce1 + hv.y) enc = ((lane * 4 + 1) << 16) | (target - ce1);
    if (hv.z > 0 && ce2 <= target && target < ce2 + hv.z) enc = ((lane * 4 + 2) << 16) | (target - ce2);
    if (hv.w > 0 && ce3 <= target && target < ce3 + hv.w) enc = ((lane * 4 + 3) << 16) | (target - ce3);
    const int benc = __builtin_amdgcn_readlane(wave_max_i32(enc), 63);
    const uint32_t bucket = (uint32_t)(benc >> 16);
    int tt = benc & 0xFFFF;

    // exact k-th smallest within bucket (expected ~2 iterations)
    uint32_t lowbar = 0u;
    while (true) {
      uint32_t mm = 0xFFFFFFFFu;
#pragma unroll
      for (int e = 0; e < 16; ++e) {
        const uint32_t kv = key[e];
        const bool cand = ((zm >> e) & 1u) && ((kv >> 24) == bucket) && (kv >= lowbar);
        const uint32_t v = cand ? kv : 0xFFFFFFFFu;
        mm = mm < v ? mm : v;
      }
      const uint32_t gmin =
          (uint32_t)__builtin_amdgcn_readlane((int)wave_min_u32(mm), 63);
      int c = 0;
#pragma unroll
      for (int e = 0; e < 16; ++e)
        c += (((zm >> e) & 1u) && key[e] == gmin) ? 1 : 0;
      const int ctot = __builtin_amdgcn_readlane(wave_iscan_add(c), 63);
      if (tt < ctot) { T = gmin; break; }
      tt -= ctot;
      lowbar = gmin + 1u;
    }
  }

  // ---- branchless masked loss, straight from the float4 components ----
  const bool nodrops = (k <= 0);
  float lsum = 0.f;
#define LOSS_ELEM(sval, e)                                                   \
  {                                                                          \
    const float s = (sval);                                                  \
    const bool z = (zm >> (e)) & 1u;                                         \
    const float cmn = __logf(1.f + __expf(-fabsf(s)));                       \
    const float x = z ? -s : s;                                              \
    const bool keep = !z || nodrops || (key[(e)] > T);                       \
    lsum += keep ? (fminf(x, 0.f) - cmn) : 0.f;                              \
  }
  LOSS_ELEM(s0.x, 0)  LOSS_ELEM(s0.y, 1)  LOSS_ELEM(s0.z, 2)  LOSS_ELEM(s0.w, 3)
  LOSS_ELEM(s1.x, 4)  LOSS_ELEM(s1.y, 5)  LOSS_ELEM(s1.z, 6)  LOSS_ELEM(s1.w, 7)
  LOSS_ELEM(s2.x, 8)  LOSS_ELEM(s2.y, 9)  LOSS_ELEM(s2.z, 10) LOSS_ELEM(s2.w, 11)
  LOSS_ELEM(s3.x, 12) LOSS_ELEM(s3.y, 13) LOSS_ELEM(s3.z, 14) LOSS_ELEM(s3.w, 15)
#undef LOSS_ELEM

  // wave reduce (DPP) -> per-wave partial
  lsum = wave_fadd(lsum);
  if (lane == 63) partials[blockIdx.x * 2 + w] = lsum;

  // ---- fused finalize: two-level done-counters (start at POISON) ----
  __threadfence();  // release: partials visible device-wide before signaling
  if (t == 0) {
    int last = 0;
    const uint32_t o1 = atomicAdd(&counters[blockIdx.x & (NGROUP - 1)], 1u);
    if (o1 == POISON + GROUP_QUOTA - 1u) {
      const uint32_t o2 = atomicAdd(&counters[NGROUP], 1u);
      if (o2 == POISON + (uint32_t)NGROUP - 1u) last = 1;
    }
    slast = last;
  }
  __syncthreads();
  if (slast) {               // exactly one block; slast is block-uniform
    __threadfence();         // acquire: see all partials
    double s = 0.0;
#pragma unroll
    for (int i = 0; i < 64; ++i) s += (double)partials[t + i * 128];
    float f = wave_fadd((float)s);
    if (lane == 63) fred[w] = f;
    __syncthreads();
    if (t == 0) {
      out[0] = (float)(-((double)fred[0] + (double)fred[1]) /
                       ((double)B_ROWS * (double)C_COLS));
    }
  }
}

extern "C" void kernel_launch(void* const* d_in, const int* in_sizes, int n_in,
                              void* d_out, int out_size, void* d_ws, size_t ws_size,
                              hipStream_t stream) {
  const float* scores = (const float*)d_in[0];
  const int* attrs = (const int*)d_in[1];
  float* out = (float*)d_out;
  float* partials = (float*)d_ws;                       // 8192 floats
  uint32_t* counters = (uint32_t*)((char*)d_ws + 8192 * sizeof(float));  // 9 uints

  attr_loss_main<<<NPAIR, 128, 0, stream>>>(scores, attrs, partials, counters, out);
}

// Round 10
// 102.996 us; speedup vs baseline: 2.6579x; 2.6579x over previous
//
#include <hip/hip_runtime.h>
#include <stdint.h>

// Problem constants
static constexpr int B_ROWS = 8192;
static constexpr int C_COLS = 1024;
static constexpr uint32_t HALF_N = 4194304u;  // B*C/2
static constexpr int NPAIR = B_ROWS / 2;      // 4096 row-pairs

__device__ __forceinline__ uint32_t rotl32(uint32_t x, int d) {
  return (x << d) | (x >> (32 - d));
}

// JAX Threefry-2x32 with key (0, 42), 20 rounds. (verified bit-exact R0-R9)
__device__ __forceinline__ void threefry2x32_k42(uint32_t& x0, uint32_t& x1) {
  const uint32_t ks0 = 0u;
  const uint32_t ks1 = 42u;
  const uint32_t ks2 = 0u ^ 42u ^ 0x1BD11BDAu;
  x0 += ks0; x1 += ks1;
#define TF_R(r) { x0 += x1; x1 = rotl32(x1, (r)); x1 ^= x0; }
  TF_R(13) TF_R(15) TF_R(26) TF_R(6)
  x0 += ks1; x1 += ks2 + 1u;
  TF_R(17) TF_R(29) TF_R(16) TF_R(24)
  x0 += ks2; x1 += ks0 + 2u;
  TF_R(13) TF_R(15) TF_R(26) TF_R(6)
  x0 += ks0; x1 += ks1 + 3u;
  TF_R(17) TF_R(29) TF_R(16) TF_R(24)
  x0 += ks1; x1 += ks2 + 4u;
  TF_R(13) TF_R(15) TF_R(26) TF_R(6)
  x0 += ks2; x1 += ks0 + 5u;
#undef TF_R
}

// ---- DPP wave64 primitives (VALU only, no DS pipe) ----
__device__ __forceinline__ int wave_iscan_add(int x) {
  x += __builtin_amdgcn_update_dpp(0, x, 0x111, 0xf, 0xf, false);
  x += __builtin_amdgcn_update_dpp(0, x, 0x112, 0xf, 0xf, false);
  x += __builtin_amdgcn_update_dpp(0, x, 0x114, 0xf, 0xf, false);
  x += __builtin_amdgcn_update_dpp(0, x, 0x118, 0xf, 0xf, false);
  x += __builtin_amdgcn_update_dpp(0, x, 0x142, 0xa, 0xf, false);
  x += __builtin_amdgcn_update_dpp(0, x, 0x143, 0xc, 0xf, false);
  return x;  // lane63 holds the wave total
}

__device__ __forceinline__ uint32_t wave_min_u32(uint32_t x) {
  uint32_t t;
#define MSTEP(ctrl, rmask)                                                   \
  t = (uint32_t)__builtin_amdgcn_update_dpp(-1, (int)x, ctrl, rmask, 0xf, false); \
  x = (t < x) ? t : x;
  MSTEP(0x111, 0xf) MSTEP(0x112, 0xf) MSTEP(0x114, 0xf) MSTEP(0x118, 0xf)
  MSTEP(0x142, 0xa) MSTEP(0x143, 0xc)
#undef MSTEP
  return x;
}

__device__ __forceinline__ int wave_max_i32(int x) {  // inputs >= -1
  int t;
#define XSTEP(ctrl, rmask)                                                   \
  t = __builtin_amdgcn_update_dpp(-1, x, ctrl, rmask, 0xf, false);           \
  x = (t > x) ? t : x;
  XSTEP(0x111, 0xf) XSTEP(0x112, 0xf) XSTEP(0x114, 0xf) XSTEP(0x118, 0xf)
  XSTEP(0x142, 0xa) XSTEP(0x143, 0xc)
#undef XSTEP
  return x;
}

__device__ __forceinline__ float wave_fadd(float x) {
#define FSTEP(ctrl, rmask)                                                   \
  x += __int_as_float(                                                       \
      __builtin_amdgcn_update_dpp(0, __float_as_int(x), ctrl, rmask, 0xf, false));
  FSTEP(0x111, 0xf) FSTEP(0x112, 0xf) FSTEP(0x114, 0xf) FSTEP(0x118, 0xf)
  FSTEP(0x142, 0xa) FSTEP(0x143, 0xc)
#undef FSTEP
  return x;
}

// Block = 128 threads = 2 waves, one row-pair (rows p, p+4096). Wave w
// computes threefry for cols [w*512, w*512+512) -> both rows' keys, keeps
// its own row's half, exchanges the other via LDS (one barrier). All global
// loads are issued at the TOP so their latency hides under the ~600-instr
// threefry chain. Separate tiny finalize kernel: a fused last-block
// finalize requires a per-block device-scope fence, which on gfx950
// (non-coherent per-XCD L2s) costs an L2 writeback per block — measured
// 3.5x regression in R9. Keep the 4 us extra launch.
__global__ __launch_bounds__(128) void attr_loss_main(
    const float* __restrict__ scores, const int* __restrict__ attrs,
    float* __restrict__ partials) {
  __shared__ int hist[2][256];
  __shared__ uint32_t xbuf[2][512];

  const int t = threadIdx.x;
  const int lane = t & 63;
  const int w = t >> 6;
  const int pair = blockIdx.x;
  const int myrow = pair + w * NPAIR;
  const int selfc0 = w * 512 + lane * 8;
  const int othc0 = (1 - w) * 512 + lane * 8;

  // ---- ALL global loads first: latency overlaps the threefry chain ----
  const float* srow = scores + (size_t)myrow * C_COLS;
  const int* arow = attrs + (size_t)myrow * C_COLS;
  const int4 a0 = *reinterpret_cast<const int4*>(arow + selfc0);
  const int4 a1 = *reinterpret_cast<const int4*>(arow + selfc0 + 4);
  const int4 a2 = *reinterpret_cast<const int4*>(arow + othc0);
  const int4 a3 = *reinterpret_cast<const int4*>(arow + othc0 + 4);
  const float4 s0 = *reinterpret_cast<const float4*>(srow + selfc0);
  const float4 s1 = *reinterpret_cast<const float4*>(srow + selfc0 + 4);
  const float4 s2 = *reinterpret_cast<const float4*>(srow + othc0);
  const float4 s3 = *reinterpret_cast<const float4*>(srow + othc0 + 4);

  // clear my wave-private histogram (same-wave LDS is program-ordered)
  *reinterpret_cast<int4*>(&hist[w][lane * 4]) = make_int4(0, 0, 0, 0);

  // threefry: 8 counter pairs -> keys for both rows of the pair
  uint32_t key[16];
#pragma unroll
  for (int j = 0; j < 8; ++j) {
    const int col = selfc0 + j;
    uint32_t x0 = (uint32_t)(pair * C_COLS + col);
    uint32_t x1 = x0 + HALF_N;
    threefry2x32_k42(x0, x1);
    const uint32_t cb = (uint32_t)col >> 1;
    const uint32_t k0 = (x0 & 0xFFFFFE00u) | cb;
    const uint32_t k1 = (x1 & 0xFFFFFE00u) | cb;
    key[j] = w ? k1 : k0;
    xbuf[w][j * 64 + lane] = w ? k0 : k1;
  }

  // zero-attr mask (attr loads have long arrived)
  uint32_t zm = 0u;
  zm |= (a0.x == 0 ? 1u : 0u) << 0;  zm |= (a0.y == 0 ? 1u : 0u) << 1;
  zm |= (a0.z == 0 ? 1u : 0u) << 2;  zm |= (a0.w == 0 ? 1u : 0u) << 3;
  zm |= (a1.x == 0 ? 1u : 0u) << 4;  zm |= (a1.y == 0 ? 1u : 0u) << 5;
  zm |= (a1.z == 0 ? 1u : 0u) << 6;  zm |= (a1.w == 0 ? 1u : 0u) << 7;
  zm |= (a2.x == 0 ? 1u : 0u) << 8;  zm |= (a2.y == 0 ? 1u : 0u) << 9;
  zm |= (a2.z == 0 ? 1u : 0u) << 10; zm |= (a2.w == 0 ? 1u : 0u) << 11;
  zm |= (a3.x == 0 ? 1u : 0u) << 12; zm |= (a3.y == 0 ? 1u : 0u) << 13;
  zm |= (a3.z == 0 ? 1u : 0u) << 14; zm |= (a3.w == 0 ? 1u : 0u) << 15;

  // self-half histogram adds: UNCONDITIONAL ds_add of the zm bit
#pragma unroll
  for (int e = 0; e < 8; ++e) {
    atomicAdd(&hist[w][key[e] >> 24], (int)((zm >> e) & 1u));
  }

  __syncthreads();
#pragma unroll
  for (int j = 0; j < 8; ++j) key[8 + j] = xbuf[1 - w][j * 64 + lane];

  // partner-half histogram adds
#pragma unroll
  for (int e = 8; e < 16; ++e) {
    atomicAdd(&hist[w][key[e] >> 24], (int)((zm >> e) & 1u));
  }

  // scan histogram, locate rank k-1 bucket
  const int4 hv = *reinterpret_cast<const int4*>(&hist[w][lane * 4]);
  const int c0 = hv.x, c1 = c0 + hv.y, c2 = c1 + hv.z, c3 = c2 + hv.w;
  const int incl = wave_iscan_add(c3);
  const int excl = incl - c3;
  const int n_zero = __builtin_amdgcn_readlane(incl, 63);
  const int k = (int)rintf(0.95f * (float)n_zero);

  uint32_t T = 0u;
  if (k > 0) {
    const int target = k - 1;
    int enc = -1;  // (bucket << 16) | within-bucket-rank; one lane sets it
    const int ce0 = excl, ce1 = excl + c0, ce2 = excl + c1, ce3 = excl + c2;
    if (hv.x > 0 && ce0 <= target && target < ce0 + hv.x) enc = ((lane * 4 + 0) << 16) | (target - ce0);
    if (hv.y > 0 && ce1 <= target && target < ce1 + hv.y) enc = ((lane * 4 + 1) << 16) | (target - ce1);
    if (hv.z > 0 && ce2 <= target && target < ce2 + hv.z) enc = ((lane * 4 + 2) << 16) | (target - ce2);
    if (hv.w > 0 && ce3 <= target && target < ce3 + hv.w) enc = ((lane * 4 + 3) << 16) | (target - ce3);
    const int benc = __builtin_amdgcn_readlane(wave_max_i32(enc), 63);
    const uint32_t bucket = (uint32_t)(benc >> 16);
    int tt = benc & 0xFFFF;

    // exact k-th smallest within bucket (expected ~1.5 iterations)
    uint32_t lowbar = 0u;
    while (true) {
      uint32_t mm = 0xFFFFFFFFu;
#pragma unroll
      for (int e = 0; e < 16; ++e) {
        const uint32_t kv = key[e];
        const bool cand = ((zm >> e) & 1u) && ((kv >> 24) == bucket) && (kv >= lowbar);
        const uint32_t v = cand ? kv : 0xFFFFFFFFu;
        mm = mm < v ? mm : v;
      }
      const uint32_t gmin = (uint32_t)__builtin_amdgcn_readlane((int)wave_min_u32(mm), 63);
      int c = 0;
#pragma unroll
      for (int e = 0; e < 16; ++e)
        c += (((zm >> e) & 1u) && key[e] == gmin) ? 1 : 0;
      const int ctot = __builtin_amdgcn_readlane(wave_iscan_add(c), 63);
      if (tt < ctot) { T = gmin; break; }
      tt -= ctot;
      lowbar = gmin + 1u;
    }
  }

  // ---- branchless masked loss, straight from the float4 components ----
  const bool nodrops = (k <= 0);
  float lsum = 0.f;
#define LOSS_ELEM(sval, e)                                                   \
  {                                                                          \
    const float s = (sval);                                                  \
    const bool z = (zm >> (e)) & 1u;                                         \
    const float cmn = __logf(1.f + __expf(-fabsf(s)));                       \
    const float x = z ? -s : s;                                              \
    const bool keep = !z || nodrops || (key[(e)] > T);                       \
    lsum += keep ? (fminf(x, 0.f) - cmn) : 0.f;                              \
  }
  LOSS_ELEM(s0.x, 0)  LOSS_ELEM(s0.y, 1)  LOSS_ELEM(s0.z, 2)  LOSS_ELEM(s0.w, 3)
  LOSS_ELEM(s1.x, 4)  LOSS_ELEM(s1.y, 5)  LOSS_ELEM(s1.z, 6)  LOSS_ELEM(s1.w, 7)
  LOSS_ELEM(s2.x, 8)  LOSS_ELEM(s2.y, 9)  LOSS_ELEM(s2.z, 10) LOSS_ELEM(s2.w, 11)
  LOSS_ELEM(s3.x, 12) LOSS_ELEM(s3.y, 13) LOSS_ELEM(s3.z, 14) LOSS_ELEM(s3.w, 15)
#undef LOSS_ELEM

  // wave reduce (DPP) -> per-wave partial
  lsum = wave_fadd(lsum);
  if (lane == 63) partials[blockIdx.x * 2 + w] = lsum;
}

__global__ __launch_bounds__(256) void finalize_kernel(
    const float* __restrict__ partials, float* __restrict__ out) {
  __shared__ double wred[4];
  const int t = threadIdx.x;
  const int lane = t & 63;
  const int w = t >> 6;
  double s = 0.0;
#pragma unroll
  for (int i = 0; i < 32; ++i) s += (double)partials[t + i * 256];
#pragma unroll
  for (int d = 32; d >= 1; d >>= 1) s += __shfl_xor(s, d, 64);
  if (lane == 0) wred[w] = s;
  __syncthreads();
  if (t == 0) {
    const double tot = wred[0] + wred[1] + wred[2] + wred[3];
    out[0] = (float)(-tot / ((double)B_ROWS * (double)C_COLS));
  }
}

extern "C" void kernel_launch(void* const* d_in, const int* in_sizes, int n_in,
                              void* d_out, int out_size, void* d_ws, size_t ws_size,
                              hipStream_t stream) {
  const float* scores = (const float*)d_in[0];
  const int* attrs = (const int*)d_in[1];
  float* out = (float*)d_out;
  float* partials = (float*)d_ws;  // 8192 floats = 32 KB scratch

  attr_loss_main<<<NPAIR, 128, 0, stream>>>(scores, attrs, partials);
  finalize_kernel<<<1, 256, 0, stream>>>(partials, out);
}